// Round 5
// baseline (181.711 us; speedup 1.0000x reference)
//
#include <hip/hip_runtime.h>
#include <math.h>

#define NB 4
#define PP 256
#define CC 151
#define RR 51
#define CM 160                 // padded C (5 tiles of 32)
#define KS 64                  // split-K: 4 i's per block
#define NROW (NB*PP)           // 1024
#define RELTOT (NB*PP*PP*RR)   // 13,369,344 floats
#define MLB 10240              // halves per l in m-layout: 8 oct * 160 c * 8 j
#define LROW 68                // LDS row stride (floats): 17*16B -> b128-aligned, 4-bank spread

typedef _Float16 half8 __attribute__((ext_vector_type(8)));
typedef float floatx16 __attribute__((ext_vector_type(16)));
typedef float float4a __attribute__((ext_vector_type(4)));              // 16B-aligned
typedef float float4u __attribute__((ext_vector_type(4), aligned(4))); // 4B-aligned ok

// ws layout (bytes): m1g, m2g, part
#define OFF_M1 ((size_t)0)
#define OFF_M2 (OFF_M1 + (size_t)CC*MLB*2)     // +3,092,480
#define OFF_PT (OFF_M2 + (size_t)CC*MLB*2)     // part: 64*1024*160*4 = 41.9 MB

// ---------------------------------------------------------------------------
// K1: streaming-friendly M layout (unchanged).
// m1g[l][oct][c][j] = w_r * M[l][c][oct*8+j]   (r = oct*8+j)
// m2g[l][oct][c][j] = w_r * M[c][l][oct*8+j]
// ---------------------------------------------------------------------------
__global__ __launch_bounds__(256) void prep_kernel(const float* __restrict__ M,
                                                   _Float16* __restrict__ m1,
                                                   _Float16* __restrict__ m2,
                                                   float* __restrict__ out) {
    const int l = blockIdx.x;      // 0..150
    const int mat = blockIdx.y;    // 0,1
    if (l == 0 && mat == 0 && threadIdx.x == 0) *out = 0.f;
    _Float16* dst = (mat ? m2 : m1) + (size_t)l * MLB;
    for (int e = threadIdx.x; e < MLB; e += 256) {
        int oct = e / 1280;
        int rem = e - oct * 1280;
        int c = rem >> 3, j = rem & 7;
        int r = oct * 8 + j;
        float v = 0.f;
        if (r < RR && c < CC) {
            size_t src = ((size_t)(mat ? c * CC + l : l * CC + c)) * RR + r;
            v = (r == 0 ? 0.5f : 0.25f) * M[src];
        }
        dst[e] = (_Float16)v;
    }
}

// ---------------------------------------------------------------------------
// K2 — COALESCED-A LDS-staged GEMM (32x32x16 MFMA).
// Post-mortem r2-r4: per-lane A loads are 204B/52KB-stride scatters; each
// wave-instr touches 32-64 cache lines -> L1/TA transaction-rate cap at
// ~2.5 TB/s regardless of pipeline depth. Fix: A staged through LDS with
// COALESCED cooperative loads (per (mat,il) the block's A set is a slab).
//   - LDS [2][128][68] f32 (68 floats = 17x16B: b128-aligned rows, 4-bank
//     spread = b128 throughput floor). Dwords 51..67 zeroed once (pad k-slots
//     must be finite: B is zero there, NaN*0 would poison acc).
//   - 8 phases (mat,il): issue B(t0,t1) -> issue next stage loads (float4,
//     lanes contiguous) -> sched_barrier -> 4 MFMA t-steps (B t2,t3
//     prefetched) -> ds_write staged regs (register-dep counted wait) ->
//     __syncthreads (drain-free: nothing outstanding). 1 barrier / 20 MFMA.
//   - B stays per-lane from L2 (16B-aligned contiguous; well coalesced).
// Grid 512 = 4 img x 2 rowblk x 64 ks; 69.6 KB LDS -> 2 blocks/CU.
// ---------------------------------------------------------------------------
__global__ __launch_bounds__(256, 2) void gemm_kernel(const float* __restrict__ rel,
                                                      const _Float16* __restrict__ m1,
                                                      const _Float16* __restrict__ m2,
                                                      const int* __restrict__ labels,
                                                      float* __restrict__ part) {
    __shared__ float bufA[2][128 * LROW];   // 2 x 34,816 B = 69,632 B
    const int tid  = threadIdx.x;
    const int ks   = blockIdx.x & 63;
    const int rbk  = (blockIdx.x >> 6) & 1;
    const int n    = blockIdx.x >> 7;
    const int wave = tid >> 6, lane = tid & 63;
    const int m32  = lane & 31, kh = lane >> 5;
    const int i0   = ks * 4;
    const int row_loc = wave * 32 + m32;          // 0..127
    const int rowimg  = rbk * 128 + row_loc;      // in-image q

    int labs[4];
    #pragma unroll
    for (int j = 0; j < 4; ++j) labs[j] = labels[n * PP + i0 + j];

    floatx16 acc[5];
    #pragma unroll
    for (int ct = 0; ct < 5; ++ct)
        #pragma unroll
        for (int r2 = 0; r2 < 16; ++r2) acc[ct][r2] = 0.f;

    // staging geometry: chunk col sc = tid&15 (fixed per thread, active sc<13),
    // rows rep*16 + (tid>>4). Chunk = 4 floats (16B), 13 chunks cover r=0..50+pad51.
    const int sc  = tid & 15;
    const int sr0 = tid >> 4;

    // one-time zero-fill of pad dwords 52..67 (both buffers, all 128 rows)
    {
        float* z = &bufA[tid >> 7][(tid & 127) * LROW + 52];
        float4a z4 = {0.f, 0.f, 0.f, 0.f};
        *(float4a*)(z)      = z4;  *(float4a*)(z + 4)  = z4;
        *(float4a*)(z + 8)  = z4;  *(float4a*)(z + 12) = z4;
    }

    // phase p = mat*4 + il; A slab for (mat,il):
    //   mat0: rel[n][i][qb..qb+128][r]  (row stride RR, slab contiguous)
    //   mat1: rel[n][qb+row][i][r]      (row stride PP*RR)
    auto stageLoad = [&](int p, float4u* sreg) {
        const int il = p & 3, mt = p >> 2, i = i0 + il;
        const size_t base = mt ? ((size_t)((n * PP + rbk * 128) * PP + i)) * RR
                               : ((size_t)((n * PP + i) * PP + rbk * 128)) * RR;
        const size_t stride = mt ? (size_t)PP * RR : (size_t)RR;
        if (sc < 13) {
            #pragma unroll
            for (int rep = 0; rep < 8; ++rep) {
                const float* s = rel + base + (size_t)(sr0 + rep * 16) * stride + sc * 4;
                if (sc < 12) {
                    sreg[rep] = *(const float4u*)s;
                } else {            // chunk 12: floats 48,49,50 + zero pad slot 51
                    float4u v; v[0] = s[0]; v[1] = s[1]; v[2] = s[2]; v[3] = 0.f;
                    sreg[rep] = v;
                }
            }
        }
    };
    auto stageWrite = [&](int buf, const float4u* sreg) {
        if (sc < 13) {
            #pragma unroll
            for (int rep = 0; rep < 8; ++rep) {
                float4a v = {sreg[rep][0], sreg[rep][1], sreg[rep][2], sreg[rep][3]};
                *(float4a*)(&bufA[buf][(sr0 + rep * 16) * LROW + sc * 4]) = v;
            }
        }
    };
    auto loadB = [&](int p, int t, half8* b) {
        const int il = p & 3, mt = p >> 2;
        const _Float16* ptr = (mt ? m2 : m1) + (size_t)labs[il] * MLB + t * 2560
                            + (size_t)(kh * 160 + m32) * 8;
        #pragma unroll
        for (int ct = 0; ct < 5; ++ct) b[ct] = *(const half8*)(ptr + ct * 256);
    };
    auto computeStep = [&](int p, int t, const half8* bv) {
        const int il = p & 3, buf = p & 1;
        const bool dz = (i0 + il) == rowimg;     // diagonal i == q -> zero A row
        const float* ap = &bufA[buf][row_loc * LROW + t * 16 + kh * 8];
        float4a lo = *(const float4a*)ap;
        float4a hi = *(const float4a*)(ap + 4);
        half8 a;
        #pragma unroll
        for (int j = 0; j < 4; ++j) {
            a[j]     = (_Float16)(dz ? 0.f : lo[j]);
            a[j + 4] = (_Float16)(dz ? 0.f : hi[j]);
        }
        #pragma unroll
        for (int ct = 0; ct < 5; ++ct)
            acc[ct] = __builtin_amdgcn_mfma_f32_32x32x16_f16(a, bv[ct], acc[ct], 0, 0, 0);
    };

    // prologue: stage phase 0 into buf0
    float4u sreg[8];
    stageLoad(0, sreg);
    stageWrite(0, sreg);
    __syncthreads();

    half8 B0[5], B1[5], B2[5], B3[5];
    #pragma unroll
    for (int p = 0; p < 8; ++p) {
        loadB(p, 0, B0);                          // first in vmem queue: t0's wait
        loadB(p, 1, B1);                          // retires only B0/B1 (in-order)
        __builtin_amdgcn_sched_barrier(0);
        if (p < 7) stageLoad(p + 1, sreg);        // HBM slab loads, overlap compute
        __builtin_amdgcn_sched_barrier(0);
        computeStep(p, 0, B0);  loadB(p, 2, B2);
        computeStep(p, 1, B1);  loadB(p, 3, B3);
        computeStep(p, 2, B2);
        computeStep(p, 3, B3);
        if (p < 7) stageWrite((p + 1) & 1, sreg); // reg-dep counted vmcnt wait
        __syncthreads();                          // drain-free: nothing outstanding
    }

    // C/D 32x32 layout (m74/m101): col = m32, row = (reg&3) + 8*(reg>>2) + 4*kh
    float* pb = part + ((size_t)ks * NROW + n * PP + rbk * 128 + wave * 32) * CM;
    #pragma unroll
    for (int ct = 0; ct < 5; ++ct)
        #pragma unroll
        for (int reg = 0; reg < 16; ++reg) {
            int row = (reg & 3) + 8 * (reg >> 2) + 4 * kh;
            pb[(size_t)row * CM + ct * 32 + m32] = acc[ct][reg];
        }
}

// ---------------------------------------------------------------------------
// K3: theta[row][c] = sum_ks part; loss = lse(theta) - theta[lab]; mean.
// ---------------------------------------------------------------------------
__global__ __launch_bounds__(256) void reduce_loss_kernel(const float* __restrict__ part,
                                                          const int* __restrict__ labels,
                                                          float* __restrict__ out) {
    __shared__ float th[CM];
    const int row = blockIdx.x;
    const int t = threadIdx.x;
    if (t < CM) {
        float s = 0.f;
        #pragma unroll
        for (int ks = 0; ks < KS; ++ks)
            s += part[((size_t)ks * NROW + row) * CM + t];
        th[t] = s;
    }
    __syncthreads();
    if (t < 64) {
        float v0 = (t < CC)       ? th[t]       : -INFINITY;
        float v1 = (t + 64 < CC)  ? th[t + 64]  : -INFINITY;
        float v2 = (t + 128 < CC) ? th[t + 128] : -INFINITY;
        float m = fmaxf(v0, fmaxf(v1, v2));
        #pragma unroll
        for (int o = 32; o > 0; o >>= 1) m = fmaxf(m, __shfl_xor(m, o, 64));
        float s = 0.f;
        if (t < CC)       s += expf(v0 - m);
        if (t + 64 < CC)  s += expf(v1 - m);
        if (t + 128 < CC) s += expf(v2 - m);
        #pragma unroll
        for (int o = 32; o > 0; o >>= 1) s += __shfl_xor(s, o, 64);
        if (t == 0) {
            atomicAdd(out, (m + logf(s) - th[labels[row]]) * (1.0f / NROW));
        }
    }
}

// ---------------------------------------------------------------------------
extern "C" void kernel_launch(void* const* d_in, const int* in_sizes, int n_in,
                              void* d_out, int out_size, void* d_ws, size_t ws_size,
                              hipStream_t stream) {
    // inputs: 0=roi_scores (unused), 1=rel_scores, 2=relationship_mat,
    //         3=roi_labels, 4=num_images (fixed B=4)
    const float* rel    = (const float*)d_in[1];
    const float* relmat = (const float*)d_in[2];
    const int*   labels = (const int*)d_in[3];
    float* out = (float*)d_out;
    char* ws = (char*)d_ws;

    _Float16* m1 = (_Float16*)(ws + OFF_M1);
    _Float16* m2 = (_Float16*)(ws + OFF_M2);
    float*  part = (float*)(ws + OFF_PT);

    prep_kernel<<<dim3(CC, 2), 256, 0, stream>>>(relmat, m1, m2, out);
    gemm_kernel<<<NB * 2 * KS, 256, 0, stream>>>(rel, m1, m2, labels, part);
    reduce_loss_kernel<<<NROW, 256, 0, stream>>>(part, labels, out);
}

// Round 6
// 166.345 us; speedup vs baseline: 1.0924x; 1.0924x over previous
//
#include <hip/hip_runtime.h>
#include <math.h>

#define NB 4
#define PP 256
#define CC 151
#define RR 51
#define CM 160                 // padded C (5 tiles of 32)
#define KS 64                  // split-K: 4 i's per block
#define NROW (NB*PP)           // 1024
#define MLB 10240              // halves per l in m-layout: 8 oct * 160 c * 8 j
#define NRELROW (NB*PP*PP)     // 262,144 rows of rel
#define CONVB (NRELROW/8)      // 32,768 conv blocks (8 rows each)
#define PREPB (CC*2)           // 302 prep blocks

typedef _Float16 half8 __attribute__((ext_vector_type(8)));
typedef _Float16 half2v __attribute__((ext_vector_type(2)));
typedef float floatx16 __attribute__((ext_vector_type(16)));

// ws layout (bytes): m1g, m2g, part, rel16
#define OFF_M1 ((size_t)0)
#define OFF_M2 (OFF_M1 + (size_t)CC*MLB*2)        // +3,092,480
#define OFF_PT (OFF_M2 + (size_t)CC*MLB*2)        // part: 64*1024*160*4 = 41.9 MB
#define OFF_R16 (OFF_PT + (size_t)KS*NROW*CM*4)   // rel16: 262144*64*2 = 33.5 MB

// ---------------------------------------------------------------------------
// K1 (fused): prep (blocks 0..301) + rel->f16 conversion (blocks 302..).
// prep: m1g[l][oct][c][j] = w_r * M[l][c][oct*8+j]   (r = oct*8+j)
//       m2g[l][oct][c][j] = w_r * M[c][l][oct*8+j]
//       w_0 = 0.5, w_{r>=1} = 0.25; zero for r >= 51 or c >= 151.
// conv: rel16[row][h] = (h<51 && a!=b) ? (_Float16)rel[row*51+h] : 0
//       where row = (n*256+a)*256+b. 128-B rows -> every 8-half MFMA
//       fragment is one 16-B-aligned dwordx4 load in K2 (was 8 dword
//       scatter loads -> the r0-r5 ~35cyc/instr TA bottleneck). Diagonal
//       (a==b) rows pre-zeroed: off_diag handled with zero gemm cost.
//       Numerics identical: same f32->f16 RTN cvt the MFMA path did.
// ---------------------------------------------------------------------------
__global__ __launch_bounds__(256) void prep_kernel(const float* __restrict__ M,
                                                   const float* __restrict__ rel,
                                                   _Float16* __restrict__ m1,
                                                   _Float16* __restrict__ m2,
                                                   _Float16* __restrict__ rel16,
                                                   float* __restrict__ out) {
    const int bid = blockIdx.x;
    if (bid < PREPB) {
        const int l = (bid < CC) ? bid : bid - CC;   // 0..150
        const int mat = (bid < CC) ? 0 : 1;
        if (bid == 0 && threadIdx.x == 0) *out = 0.f;
        _Float16* dst = (mat ? m2 : m1) + (size_t)l * MLB;
        for (int e = threadIdx.x; e < MLB; e += 256) {
            int oct = e / 1280;
            int rem = e - oct * 1280;
            int c = rem >> 3, j = rem & 7;
            int r = oct * 8 + j;
            float v = 0.f;
            if (r < RR && c < CC) {
                size_t src = ((size_t)(mat ? c * CC + l : l * CC + c)) * RR + r;
                v = (r == 0 ? 0.5f : 0.25f) * M[src];
            }
            dst[e] = (_Float16)v;
        }
    } else {
        // conversion: 8 rel-rows per block, thread t -> row row0+(t>>5),
        // halves h0=2*(t&31), h1=h0+1. In-loads stride-2-dword coalesced,
        // out-stores fully contiguous 4-B.
        const int t = threadIdx.x;
        const size_t row = (size_t)(bid - PREPB) * 8 + (t >> 5);
        const int d  = t & 31;
        const int h0 = 2 * d;
        const int a  = ((int)row >> 8) & 255;
        const int b  = (int)row & 255;
        const bool live = (a != b);
        const float* src = rel + row * RR;
        float v0 = (live && h0 < RR)     ? src[h0]     : 0.f;
        float v1 = (live && h0 + 1 < RR) ? src[h0 + 1] : 0.f;
        half2v p;
        p[0] = (_Float16)v0;
        p[1] = (_Float16)v1;
        *(half2v*)(rel16 + row * 64 + h0) = p;
    }
}

// ---------------------------------------------------------------------------
// K2 (fused transpose+GEMM, 32x32x16 MFMA) — round-0 structure + f16 A:
// part[ks][row q][c] = sum_{i in chunk, r} rel[n,i,q,r]*w_r*M[lab_i,c,r]
//                                        + rel[n,q,i,r]*w_r*M[c,lab_i,r]
// Block: 128 rows x 160 c; 4 waves x (32 rows x 5 c-tiles). 32 steps of k=16
// (4 i x 2 mat x 4 k-steps). B staged as one contiguous 5 KB global_load_lds
// burst per step (double-buffered). A: ONE dwordx4 (8 halves) per lane per
// step from rel16 — r0's 8-dword scatter (the measured ~35 cyc/vmem-instr TA
// cap) collapsed 8x. No cvt, no diagonal cndmask (pre-zeroed rows).
// Grid 512 = 4 img x 2 rowblk x 64 ks.
// ---------------------------------------------------------------------------
__global__ __launch_bounds__(256) void gemm_kernel(const _Float16* __restrict__ rel16,
                                                   const _Float16* __restrict__ m1,
                                                   const _Float16* __restrict__ m2,
                                                   const int* __restrict__ labels,
                                                   float* __restrict__ part) {
    __shared__ _Float16 Bt[2][2560];       // 2 x 5 KB
    const int tid  = threadIdx.x;
    const int ks   = blockIdx.x & 63;
    const int rbk  = (blockIdx.x >> 6) & 1;
    const int n    = blockIdx.x >> 7;
    const int wave = tid >> 6, lane = tid & 63;
    const int m32  = lane & 31, kh = lane >> 5;
    const int i0   = ks * 4;
    const int rowimg = rbk * 128 + wave * 32 + m32;   // this lane's A row (q, in-image)

    int labs[4];
    #pragma unroll
    for (int j = 0; j < 4; ++j) labs[j] = labels[n * PP + i0 + j];

    floatx16 acc[5];
    #pragma unroll
    for (int ct = 0; ct < 5; ++ct)
        #pragma unroll
        for (int r2 = 0; r2 < 16; ++r2) acc[ct][r2] = 0.f;

    // step h = (i_loc<<3) | (mat<<2) | t ; t = k16-step within the 64 slots
    auto stageB = [&](int h, int buf) {
        const int il = h >> 3, mh = (h >> 2) & 1, t = h & 3;
        const _Float16* base = (mh ? m2 : m1) + (size_t)labs[il] * MLB + t * 2560;
        #pragma unroll
        for (int j = 0; j < 2; ++j) {
            int s = j * 256 + tid;               // 320 chunks of 16B, contiguous
            if (s < 320) {
                __builtin_amdgcn_global_load_lds(
                    (const __attribute__((address_space(1))) unsigned int*)(base + s * 8),
                    (__attribute__((address_space(3))) unsigned int*)(&Bt[buf][(size_t)s * 8]),
                    16, 0, 0);
            }
        }
    };
    auto loadA = [&](int h, half8* a) {
        const int il = h >> 3, mh = (h >> 2) & 1, t = h & 3;
        const int i = i0 + il;
        const size_t row = mh ? ((size_t)(n * PP + rowimg) * PP + i)
                              : ((size_t)(n * PP + i) * PP + rowimg);
        *a = *(const half8*)(rel16 + row * 64 + t * 16 + kh * 8);   // 16-B aligned
    };

    stageB(0, 0);
    half8 av;
    loadA(0, &av);

    #pragma unroll 2
    for (int h = 0; h < 32; ++h) {
        __syncthreads();                       // B(h) staged, av(h) in regs
        if (h < 31) stageB(h + 1, (h + 1) & 1);
        half8 avn;
        if (h < 31) loadA(h + 1, &avn);

        // B-frag: n = m32 (+ct*32), k = kh*8+j -> chunk (kh*160 + ct*32 + m32)
        const _Float16* bb = &Bt[h & 1][(size_t)(kh * 160 + m32) * 8];
        #pragma unroll
        for (int ct = 0; ct < 5; ++ct) {
            half8 b = *(const half8*)(bb + ct * 256);
            acc[ct] = __builtin_amdgcn_mfma_f32_32x32x16_f16(av, b, acc[ct], 0, 0, 0);
        }
        av = avn;
    }

    // C/D 32x32 layout (m74/m101): col = m32, row = (reg&3) + 8*(reg>>2) + 4*kh
    float* pb = part + ((size_t)ks * NROW + n * PP + rbk * 128 + wave * 32) * CM;
    #pragma unroll
    for (int ct = 0; ct < 5; ++ct)
        #pragma unroll
        for (int reg = 0; reg < 16; ++reg) {
            int row = (reg & 3) + 8 * (reg >> 2) + 4 * kh;
            pb[(size_t)row * CM + ct * 32 + m32] = acc[ct][reg];
        }
}

// ---------------------------------------------------------------------------
// K3: theta[row][c] = sum_ks part; loss = lse(theta) - theta[lab]; mean.
// ---------------------------------------------------------------------------
__global__ __launch_bounds__(256) void reduce_loss_kernel(const float* __restrict__ part,
                                                          const int* __restrict__ labels,
                                                          float* __restrict__ out) {
    __shared__ float th[CM];
    const int row = blockIdx.x;
    const int t = threadIdx.x;
    if (t < CM) {
        float s = 0.f;
        #pragma unroll
        for (int ks = 0; ks < KS; ++ks)
            s += part[((size_t)ks * NROW + row) * CM + t];
        th[t] = s;
    }
    __syncthreads();
    if (t < 64) {
        float v0 = (t < CC)       ? th[t]       : -INFINITY;
        float v1 = (t + 64 < CC)  ? th[t + 64]  : -INFINITY;
        float v2 = (t + 128 < CC) ? th[t + 128] : -INFINITY;
        float m = fmaxf(v0, fmaxf(v1, v2));
        #pragma unroll
        for (int o = 32; o > 0; o >>= 1) m = fmaxf(m, __shfl_xor(m, o, 64));
        float s = 0.f;
        if (t < CC)       s += expf(v0 - m);
        if (t + 64 < CC)  s += expf(v1 - m);
        if (t + 128 < CC) s += expf(v2 - m);
        #pragma unroll
        for (int o = 32; o > 0; o >>= 1) s += __shfl_xor(s, o, 64);
        if (t == 0) {
            atomicAdd(out, (m + logf(s) - th[labels[row]]) * (1.0f / NROW));
        }
    }
}

// ---------------------------------------------------------------------------
extern "C" void kernel_launch(void* const* d_in, const int* in_sizes, int n_in,
                              void* d_out, int out_size, void* d_ws, size_t ws_size,
                              hipStream_t stream) {
    // inputs: 0=roi_scores (unused), 1=rel_scores, 2=relationship_mat,
    //         3=roi_labels, 4=num_images (fixed B=4)
    const float* rel    = (const float*)d_in[1];
    const float* relmat = (const float*)d_in[2];
    const int*   labels = (const int*)d_in[3];
    float* out = (float*)d_out;
    char* ws = (char*)d_ws;

    _Float16* m1    = (_Float16*)(ws + OFF_M1);
    _Float16* m2    = (_Float16*)(ws + OFF_M2);
    float*    part  = (float*)(ws + OFF_PT);
    _Float16* rel16 = (_Float16*)(ws + OFF_R16);

    prep_kernel<<<PREPB + CONVB, 256, 0, stream>>>(relmat, rel, m1, m2, rel16, out);
    gemm_kernel<<<NB * 2 * KS, 256, 0, stream>>>(rel16, m1, m2, labels, part);
    reduce_loss_kernel<<<NROW, 256, 0, stream>>>(part, labels, out);
}

// Round 7
// 149.817 us; speedup vs baseline: 1.2129x; 1.1103x over previous
//
#include <hip/hip_runtime.h>
#include <math.h>

#define NB 4
#define PP 256
#define CC 151
#define RR 51
#define CM 160                 // padded C (5 tiles of 32)
#define KS 64                  // split-K: 4 i's per block
#define NROW (NB*PP)           // 1024
#define MLB 10240              // halves per l in m-layout: 8 oct * 160 c * 8 j
#define NRELROW (NB*PP*PP)     // 262,144 rows of rel
#define CONVB (NRELROW/8)      // 32,768 conv blocks (8 rows each)
#define PREPB (CC*2)           // 302 prep blocks

typedef _Float16 half8 __attribute__((ext_vector_type(8)));
typedef _Float16 half2v __attribute__((ext_vector_type(2)));
typedef float floatx16 __attribute__((ext_vector_type(16)));

// ws layout (bytes): m1g, m2g, part, rel16
#define OFF_M1 ((size_t)0)
#define OFF_M2 (OFF_M1 + (size_t)CC*MLB*2)        // +3,092,480
#define OFF_PT (OFF_M2 + (size_t)CC*MLB*2)        // part: 1024*64*160*4 = 41.9 MB
#define OFF_R16 (OFF_PT + (size_t)NROW*KS*CM*4)   // rel16: 262144*64*2 = 33.5 MB

// ---------------------------------------------------------------------------
// K1 (fused): prep (blocks 0..301) + rel->f16 conversion (blocks 302..).
// prep: m1g[l][oct][c][j] = w_r * M[l][c][oct*8+j]   (r = oct*8+j)
//       m2g[l][oct][c][j] = w_r * M[c][l][oct*8+j]
//       w_0 = 0.5, w_{r>=1} = 0.25; zero for r >= 51 or c >= 151.
// conv: rel16[row][h] = (h<51 && a!=b) ? (_Float16)rel[row*51+h] : 0
//       128-B rows -> every 8-half MFMA fragment is one 16-B dwordx4 in K2.
//       Diagonal (a==b) rows pre-zeroed (off_diag free in gemm).
// ---------------------------------------------------------------------------
__global__ __launch_bounds__(256) void prep_kernel(const float* __restrict__ M,
                                                   const float* __restrict__ rel,
                                                   _Float16* __restrict__ m1,
                                                   _Float16* __restrict__ m2,
                                                   _Float16* __restrict__ rel16,
                                                   float* __restrict__ out) {
    const int bid = blockIdx.x;
    if (bid < PREPB) {
        const int l = (bid < CC) ? bid : bid - CC;   // 0..150
        const int mat = (bid < CC) ? 0 : 1;
        if (bid == 0 && threadIdx.x == 0) *out = 0.f;
        _Float16* dst = (mat ? m2 : m1) + (size_t)l * MLB;
        for (int e = threadIdx.x; e < MLB; e += 256) {
            int oct = e / 1280;
            int rem = e - oct * 1280;
            int c = rem >> 3, j = rem & 7;
            int r = oct * 8 + j;
            float v = 0.f;
            if (r < RR && c < CC) {
                size_t src = ((size_t)(mat ? c * CC + l : l * CC + c)) * RR + r;
                v = (r == 0 ? 0.5f : 0.25f) * M[src];
            }
            dst[e] = (_Float16)v;
        }
    } else {
        // conversion: 8 rel-rows per block, thread t -> row row0+(t>>5),
        // halves h0=2*(t&31), h1=h0+1.
        const int t = threadIdx.x;
        const size_t row = (size_t)(bid - PREPB) * 8 + (t >> 5);
        const int d  = t & 31;
        const int h0 = 2 * d;
        const int a  = ((int)row >> 8) & 255;
        const int b  = (int)row & 255;
        const bool live = (a != b);
        const float* src = rel + row * RR;
        float v0 = (live && h0 < RR)     ? src[h0]     : 0.f;
        float v1 = (live && h0 + 1 < RR) ? src[h0 + 1] : 0.f;
        half2v p;
        p[0] = (_Float16)v0;
        p[1] = (_Float16)v1;
        *(half2v*)(rel16 + row * 64 + h0) = p;
    }
}

// ---------------------------------------------------------------------------
// K2 (fused transpose+GEMM, 32x32x16 MFMA) — counted-vmcnt ring-4 pipeline
// (m201 T3+T4 pattern, now viable because per-step traffic is tiny+uniform):
//   - per thread per step: EXACTLY 3 vmem ops — B slab 5120 B split as one
//     16-B DMA (4096 B) + one 4-B DMA (1024 B) per thread, plus one A dwordx4
//     (8 halves) from rel16.
//   - ring of 4 B-buffers, prefetch distance 2. Per step:
//       stage(h+2) -> s_waitcnt vmcnt(6) -> s_barrier -> 5x MFMA
//     vmcnt(6) retires exactly step h's {A,B}, keeps h+1,h+2 in flight:
//     NO vmcnt(0) drain anywhere in the loop (r0's __syncthreads cost
//     ~400 cyc/step). Tail: vmcnt(3), vmcnt(0). WAR-safe: buffer rewritten
//     one full barrier after its last ds_read (ring-4).
//   - A held in 4 rotating half8 regs (loop fully unrolled -> static idx).
// Grid 512 = 4 img x 2 rowblk x 64 ks; LDS 20 KB; 2 blocks/CU.
// ---------------------------------------------------------------------------
__global__ __launch_bounds__(256) void gemm_kernel(const _Float16* __restrict__ rel16,
                                                   const _Float16* __restrict__ m1,
                                                   const _Float16* __restrict__ m2,
                                                   const int* __restrict__ labels,
                                                   float* __restrict__ part) {
    __shared__ _Float16 Bt[4][2560];       // 4 x 5 KB
    const int tid  = threadIdx.x;
    const int ks   = blockIdx.x & 63;
    const int rbk  = (blockIdx.x >> 6) & 1;
    const int n    = blockIdx.x >> 7;
    const int wave = tid >> 6, lane = tid & 63;
    const int m32  = lane & 31, kh = lane >> 5;
    const int i0   = ks * 4;
    const int rowimg = rbk * 128 + wave * 32 + m32;   // this lane's A row (q, in-image)

    int labs[4];
    #pragma unroll
    for (int j = 0; j < 4; ++j) labs[j] = labels[n * PP + i0 + j];

    floatx16 acc[5];
    #pragma unroll
    for (int ct = 0; ct < 5; ++ct)
        #pragma unroll
        for (int r2 = 0; r2 < 16; ++r2) acc[ct][r2] = 0.f;

    half8 aS[4];

    // step h = (i_loc<<3) | (mat<<2) | t ; t = k16-step within the 64 slots
    auto stageB = [&](int h, int buf) {
        const int il = h >> 3, mh = (h >> 2) & 1, t = h & 3;
        const _Float16* base = (mh ? m2 : m1) + (size_t)labs[il] * MLB + t * 2560;
        // 16-B chunk: threads cover halves [0,2048); uniform 1 op/thread
        __builtin_amdgcn_global_load_lds(
            (const __attribute__((address_space(1))) unsigned int*)(base + tid * 8),
            (__attribute__((address_space(3))) unsigned int*)(&Bt[buf][tid * 8]),
            16, 0, 0);
        // 4-B chunk: halves [2048,2560); uniform 1 op/thread
        __builtin_amdgcn_global_load_lds(
            (const __attribute__((address_space(1))) unsigned int*)(base + 2048 + tid * 2),
            (__attribute__((address_space(3))) unsigned int*)(&Bt[buf][2048 + tid * 2]),
            4, 0, 0);
    };
    auto loadA = [&](int h) {
        const int il = h >> 3, mh = (h >> 2) & 1, t = h & 3;
        const int i = i0 + il;
        const size_t row = mh ? ((size_t)(n * PP + rowimg) * PP + i)
                              : ((size_t)(n * PP + i) * PP + rowimg);
        aS[h & 3] = *(const half8*)(rel16 + row * 64 + t * 16 + kh * 8);  // 16-B aligned
    };
    auto computeStep = [&](int h) {
        // B-frag: n = m32 (+ct*32), k = kh*8+j -> chunk (kh*160 + ct*32 + m32)
        const _Float16* bb = &Bt[h & 3][(size_t)(kh * 160 + m32) * 8];
        #pragma unroll
        for (int ct = 0; ct < 5; ++ct) {
            half8 b = *(const half8*)(bb + ct * 256);
            acc[ct] = __builtin_amdgcn_mfma_f32_32x32x16_f16(aS[h & 3], b, acc[ct], 0, 0, 0);
        }
    };

    // prologue: steps 0,1 in flight (6 ops/thread)
    stageB(0, 0); loadA(0);
    stageB(1, 1); loadA(1);

    #pragma unroll
    for (int h = 0; h < 32; ++h) {
        if (h + 2 < 32) { stageB(h + 2, (h + 2) & 3); loadA(h + 2); }
        // retire step h's {B DMA, A load}; keep h+1 (,h+2) in flight (3 ops each)
        if (h < 30)       asm volatile("s_waitcnt vmcnt(6)" ::: "memory");
        else if (h == 30) asm volatile("s_waitcnt vmcnt(3)" ::: "memory");
        else              asm volatile("s_waitcnt vmcnt(0)" ::: "memory");
        __builtin_amdgcn_s_barrier();
        computeStep(h);
    }

    // C/D 32x32 layout (m74/m101): col = m32, row = (reg&3) + 8*(reg>>2) + 4*kh
    // part layout: [row][ks][c] -> K3 reads a contiguous 40-KB panel per row.
    float* pb = part + ((size_t)(n * PP + rbk * 128 + wave * 32) * KS + ks) * CM;
    #pragma unroll
    for (int ct = 0; ct < 5; ++ct)
        #pragma unroll
        for (int reg = 0; reg < 16; ++reg) {
            int row = (reg & 3) + 8 * (reg >> 2) + 4 * kh;
            pb[(size_t)row * KS * CM + ct * 32 + m32] = acc[ct][reg];
        }
}

// ---------------------------------------------------------------------------
// K3: theta[row][c] = sum_ks part[row][ks][c]; loss = lse - theta[lab]; mean.
// part panel per row is contiguous (40 KB) -> streaming reads.
// ---------------------------------------------------------------------------
__global__ __launch_bounds__(256) void reduce_loss_kernel(const float* __restrict__ part,
                                                          const int* __restrict__ labels,
                                                          float* __restrict__ out) {
    __shared__ float th[CM];
    const int row = blockIdx.x;
    const int t = threadIdx.x;
    if (t < CM) {
        const float* p = part + (size_t)row * KS * CM + t;
        float s = 0.f;
        #pragma unroll
        for (int ks = 0; ks < KS; ++ks)
            s += p[ks * CM];
        th[t] = s;
    }
    __syncthreads();
    if (t < 64) {
        float v0 = (t < CC)       ? th[t]       : -INFINITY;
        float v1 = (t + 64 < CC)  ? th[t + 64]  : -INFINITY;
        float v2 = (t + 128 < CC) ? th[t + 128] : -INFINITY;
        float m = fmaxf(v0, fmaxf(v1, v2));
        #pragma unroll
        for (int o = 32; o > 0; o >>= 1) m = fmaxf(m, __shfl_xor(m, o, 64));
        float s = 0.f;
        if (t < CC)       s += expf(v0 - m);
        if (t + 64 < CC)  s += expf(v1 - m);
        if (t + 128 < CC) s += expf(v2 - m);
        #pragma unroll
        for (int o = 32; o > 0; o >>= 1) s += __shfl_xor(s, o, 64);
        if (t == 0) {
            atomicAdd(out, (m + logf(s) - th[labels[row]]) * (1.0f / NROW));
        }
    }
}

// ---------------------------------------------------------------------------
extern "C" void kernel_launch(void* const* d_in, const int* in_sizes, int n_in,
                              void* d_out, int out_size, void* d_ws, size_t ws_size,
                              hipStream_t stream) {
    // inputs: 0=roi_scores (unused), 1=rel_scores, 2=relationship_mat,
    //         3=roi_labels, 4=num_images (fixed B=4)
    const float* rel    = (const float*)d_in[1];
    const float* relmat = (const float*)d_in[2];
    const int*   labels = (const int*)d_in[3];
    float* out = (float*)d_out;
    char* ws = (char*)d_ws;

    _Float16* m1    = (_Float16*)(ws + OFF_M1);
    _Float16* m2    = (_Float16*)(ws + OFF_M2);
    float*    part  = (float*)(ws + OFF_PT);
    _Float16* rel16 = (_Float16*)(ws + OFF_R16);

    prep_kernel<<<PREPB + CONVB, 256, 0, stream>>>(relmat, rel, m1, m2, rel16, out);
    gemm_kernel<<<NB * 2 * KS, 256, 0, stream>>>(rel16, m1, m2, labels, part);
    reduce_loss_kernel<<<NROW, 256, 0, stream>>>(part, labels, out);
}

// Round 8
// 147.301 us; speedup vs baseline: 1.2336x; 1.0171x over previous
//
#include <hip/hip_runtime.h>
#include <math.h>

#define NB 4
#define PP 256
#define CC 151
#define RR 51
#define CM 160                 // padded C (5 tiles of 32)
#define KS 32                  // split-K: 8 i's per block (r7: 64/4i; part halved)
#define NROW (NB*PP)           // 1024
#define MLB 10240              // halves per l in m-layout: 8 oct * 160 c * 8 j
#define NRELROW (NB*PP*PP)     // 262,144 rows of rel
#define CONVB (NRELROW/8)      // 32,768 conv blocks (8 rows each)
#define PREPB (CC*2)           // 302 prep blocks

typedef _Float16 half8 __attribute__((ext_vector_type(8)));
typedef _Float16 half2v __attribute__((ext_vector_type(2)));
typedef float floatx16 __attribute__((ext_vector_type(16)));

// ws layout (bytes): m1g, m2g, part, rel16
#define OFF_M1 ((size_t)0)
#define OFF_M2 (OFF_M1 + (size_t)CC*MLB*2)        // +3,092,480
#define OFF_PT (OFF_M2 + (size_t)CC*MLB*2)        // part: 1024*32*160*4 = 21.0 MB
#define OFF_R16 (OFF_PT + (size_t)NROW*KS*CM*4)   // rel16: 262144*64*2 = 33.5 MB

// ---------------------------------------------------------------------------
// K1 (fused): prep (blocks 0..301) + rel->f16 conversion (blocks 302..).
// prep: m1g[l][oct][c][j] = w_r * M[l][c][oct*8+j]   (r = oct*8+j)
//       m2g[l][oct][c][j] = w_r * M[c][l][oct*8+j]
//       w_0 = 0.5, w_{r>=1} = 0.25; zero for r >= 51 or c >= 151.
// conv: rel16[row][h] = (h<51 && a!=b) ? (_Float16)rel[row*51+h] : 0
//       128-B rows -> every 8-half MFMA fragment is one 16-B dwordx4 in K2.
//       Diagonal (a==b) rows pre-zeroed (off_diag free in gemm).
// ---------------------------------------------------------------------------
__global__ __launch_bounds__(256) void prep_kernel(const float* __restrict__ M,
                                                   const float* __restrict__ rel,
                                                   _Float16* __restrict__ m1,
                                                   _Float16* __restrict__ m2,
                                                   _Float16* __restrict__ rel16,
                                                   float* __restrict__ out) {
    const int bid = blockIdx.x;
    if (bid < PREPB) {
        const int l = (bid < CC) ? bid : bid - CC;   // 0..150
        const int mat = (bid < CC) ? 0 : 1;
        if (bid == 0 && threadIdx.x == 0) *out = 0.f;
        _Float16* dst = (mat ? m2 : m1) + (size_t)l * MLB;
        for (int e = threadIdx.x; e < MLB; e += 256) {
            int oct = e / 1280;
            int rem = e - oct * 1280;
            int c = rem >> 3, j = rem & 7;
            int r = oct * 8 + j;
            float v = 0.f;
            if (r < RR && c < CC) {
                size_t src = ((size_t)(mat ? c * CC + l : l * CC + c)) * RR + r;
                v = (r == 0 ? 0.5f : 0.25f) * M[src];
            }
            dst[e] = (_Float16)v;
        }
    } else {
        // conversion: 8 rel-rows per block, thread t -> row row0+(t>>5),
        // halves h0=2*(t&31), h1=h0+1.
        const int t = threadIdx.x;
        const size_t row = (size_t)(bid - PREPB) * 8 + (t >> 5);
        const int d  = t & 31;
        const int h0 = 2 * d;
        const int a  = ((int)row >> 8) & 255;
        const int b  = (int)row & 255;
        const bool live = (a != b);
        const float* src = rel + row * RR;
        float v0 = (live && h0 < RR)     ? src[h0]     : 0.f;
        float v1 = (live && h0 + 1 < RR) ? src[h0 + 1] : 0.f;
        half2v p;
        p[0] = (_Float16)v0;
        p[1] = (_Float16)v1;
        *(half2v*)(rel16 + row * 64 + h0) = p;
    }
}

// ---------------------------------------------------------------------------
// K2 (fused transpose+GEMM, 32x32x16 MFMA) — counted-vmcnt pipeline,
// KS=32 / distance-3 / ring-6 (r7's proven T3+T4 structure, deepened):
//   - per thread per step: EXACTLY 3 vmem ops — B slab 5120 B as one 16-B
//     DMA + one 4-B DMA per thread, plus one A dwordx4 (8 halves) of rel16.
//   - KS 64->32 halves the part round-trip (saves ~42 MB HBM) at the cost
//     of 1 block/CU; compensated by prefetch distance 3 (issue->use ~3x350
//     cyc of own work covers ~900-cyc HBM latency without a second block).
//   - ring of 6 B-buffers (30 KB). Per step:
//       stage(h+3) -> s_waitcnt vmcnt(9) -> s_barrier -> 5x MFMA
//     vmcnt(9) retires exactly step h's {A,B}; h+1..h+3 stay in flight;
//     no vmcnt(0) drain in the loop. Tail: 6/3/0. WAR-safe: buffer
//     rewritten >=2 barriers after its last ds_read.
//   - A held in 4 rotating half8 regs (full unroll -> static indices).
// Grid 256 = 4 img x 2 rowblk x 32 ks; 64 K-steps (8 i x 2 mat x 4 t).
// ---------------------------------------------------------------------------
__global__ __launch_bounds__(256) void gemm_kernel(const _Float16* __restrict__ rel16,
                                                   const _Float16* __restrict__ m1,
                                                   const _Float16* __restrict__ m2,
                                                   const int* __restrict__ labels,
                                                   float* __restrict__ part) {
    __shared__ _Float16 Bt[6][2560];       // 6 x 5 KB = 30 KB
    const int tid  = threadIdx.x;
    const int ks   = blockIdx.x & 31;
    const int rbk  = (blockIdx.x >> 5) & 1;
    const int n    = blockIdx.x >> 6;
    const int wave = tid >> 6, lane = tid & 63;
    const int m32  = lane & 31, kh = lane >> 5;
    const int i0   = ks * 8;
    const int rowimg = rbk * 128 + wave * 32 + m32;   // this lane's A row (q, in-image)

    int labs[8];
    #pragma unroll
    for (int j = 0; j < 8; ++j) labs[j] = labels[n * PP + i0 + j];

    floatx16 acc[5];
    #pragma unroll
    for (int ct = 0; ct < 5; ++ct)
        #pragma unroll
        for (int r2 = 0; r2 < 16; ++r2) acc[ct][r2] = 0.f;

    half8 aS[4];

    // step h = (i_loc<<3) | (mat<<2) | t ; il 0..7, t = k16-step
    auto stageB = [&](int h, int buf) {
        const int il = h >> 3, mh = (h >> 2) & 1, t = h & 3;
        const _Float16* base = (mh ? m2 : m1) + (size_t)labs[il] * MLB + t * 2560;
        // 16-B chunk: threads cover halves [0,2048); uniform 1 op/thread
        __builtin_amdgcn_global_load_lds(
            (const __attribute__((address_space(1))) unsigned int*)(base + tid * 8),
            (__attribute__((address_space(3))) unsigned int*)(&Bt[buf][tid * 8]),
            16, 0, 0);
        // 4-B chunk: halves [2048,2560); uniform 1 op/thread
        __builtin_amdgcn_global_load_lds(
            (const __attribute__((address_space(1))) unsigned int*)(base + 2048 + tid * 2),
            (__attribute__((address_space(3))) unsigned int*)(&Bt[buf][2048 + tid * 2]),
            4, 0, 0);
    };
    auto loadA = [&](int h) {
        const int il = h >> 3, mh = (h >> 2) & 1, t = h & 3;
        const int i = i0 + il;
        const size_t row = mh ? ((size_t)(n * PP + rowimg) * PP + i)
                              : ((size_t)(n * PP + i) * PP + rowimg);
        aS[h & 3] = *(const half8*)(rel16 + row * 64 + t * 16 + kh * 8);  // 16-B aligned
    };
    auto computeStep = [&](int h) {
        // B-frag: n = m32 (+ct*32), k = kh*8+j -> chunk (kh*160 + ct*32 + m32)
        const _Float16* bb = &Bt[h % 6][(size_t)(kh * 160 + m32) * 8];
        #pragma unroll
        for (int ct = 0; ct < 5; ++ct) {
            half8 b = *(const half8*)(bb + ct * 256);
            acc[ct] = __builtin_amdgcn_mfma_f32_32x32x16_f16(aS[h & 3], b, acc[ct], 0, 0, 0);
        }
    };

    // prologue: steps 0,1,2 in flight (9 ops/thread)
    stageB(0, 0); loadA(0);
    stageB(1, 1); loadA(1);
    stageB(2, 2); loadA(2);

    #pragma unroll
    for (int h = 0; h < 64; ++h) {
        if (h + 3 < 64) { stageB(h + 3, (h + 3) % 6); loadA(h + 3); }
        // retire step h's {B DMA x2, A load}; keep h+1..h+3 in flight (3 each)
        if (h <= 60)      asm volatile("s_waitcnt vmcnt(9)" ::: "memory");
        else if (h == 61) asm volatile("s_waitcnt vmcnt(6)" ::: "memory");
        else if (h == 62) asm volatile("s_waitcnt vmcnt(3)" ::: "memory");
        else              asm volatile("s_waitcnt vmcnt(0)" ::: "memory");
        __builtin_amdgcn_s_barrier();
        computeStep(h);
    }

    // C/D 32x32 layout (m74/m101): col = m32, row = (reg&3) + 8*(reg>>2) + 4*kh
    // part layout: [row][ks][c] -> K3 reads a contiguous 20-KB panel per row.
    float* pb = part + ((size_t)(n * PP + rbk * 128 + wave * 32) * KS + ks) * CM;
    #pragma unroll
    for (int ct = 0; ct < 5; ++ct)
        #pragma unroll
        for (int reg = 0; reg < 16; ++reg) {
            int row = (reg & 3) + 8 * (reg >> 2) + 4 * kh;
            pb[(size_t)row * KS * CM + ct * 32 + m32] = acc[ct][reg];
        }
}

// ---------------------------------------------------------------------------
// K3: theta[row][c] = sum_ks part[row][ks][c]; loss = lse - theta[lab]; mean.
// part panel per row is contiguous (20 KB) -> streaming reads.
// ---------------------------------------------------------------------------
__global__ __launch_bounds__(256) void reduce_loss_kernel(const float* __restrict__ part,
                                                          const int* __restrict__ labels,
                                                          float* __restrict__ out) {
    __shared__ float th[CM];
    const int row = blockIdx.x;
    const int t = threadIdx.x;
    if (t < CM) {
        const float* p = part + (size_t)row * KS * CM + t;
        float s = 0.f;
        #pragma unroll
        for (int ks = 0; ks < KS; ++ks)
            s += p[ks * CM];
        th[t] = s;
    }
    __syncthreads();
    if (t < 64) {
        float v0 = (t < CC)       ? th[t]       : -INFINITY;
        float v1 = (t + 64 < CC)  ? th[t + 64]  : -INFINITY;
        float v2 = (t + 128 < CC) ? th[t + 128] : -INFINITY;
        float m = fmaxf(v0, fmaxf(v1, v2));
        #pragma unroll
        for (int o = 32; o > 0; o >>= 1) m = fmaxf(m, __shfl_xor(m, o, 64));
        float s = 0.f;
        if (t < CC)       s += expf(v0 - m);
        if (t + 64 < CC)  s += expf(v1 - m);
        if (t + 128 < CC) s += expf(v2 - m);
        #pragma unroll
        for (int o = 32; o > 0; o >>= 1) s += __shfl_xor(s, o, 64);
        if (t == 0) {
            atomicAdd(out, (m + logf(s) - th[labels[row]]) * (1.0f / NROW));
        }
    }
}

// ---------------------------------------------------------------------------
extern "C" void kernel_launch(void* const* d_in, const int* in_sizes, int n_in,
                              void* d_out, int out_size, void* d_ws, size_t ws_size,
                              hipStream_t stream) {
    // inputs: 0=roi_scores (unused), 1=rel_scores, 2=relationship_mat,
    //         3=roi_labels, 4=num_images (fixed B=4)
    const float* rel    = (const float*)d_in[1];
    const float* relmat = (const float*)d_in[2];
    const int*   labels = (const int*)d_in[3];
    float* out = (float*)d_out;
    char* ws = (char*)d_ws;

    _Float16* m1    = (_Float16*)(ws + OFF_M1);
    _Float16* m2    = (_Float16*)(ws + OFF_M2);
    float*    part  = (float*)(ws + OFF_PT);
    _Float16* rel16 = (_Float16*)(ws + OFF_R16);

    prep_kernel<<<PREPB + CONVB, 256, 0, stream>>>(relmat, rel, m1, m2, rel16, out);
    gemm_kernel<<<NB * 2 * KS, 256, 0, stream>>>(rel16, m1, m2, labels, part);
    reduce_loss_kernel<<<NROW, 256, 0, stream>>>(part, labels, out);
}